// Round 2
// baseline (796.738 us; speedup 1.0000x reference)
//
#include <hip/hip_runtime.h>
#include <math.h>

#define NBINS 10
#define TOT_F 51200000.0f
#define BMARG 2e-5f       // bin-edge safety margin for the rcp fast path
#define NREPL 64          // plan-B atomic replica lines
#define REPL_STRIDE 16

typedef float f32x4 __attribute__((ext_vector_type(4)));

// --- numpy float32 np.exp replica (SIMD path: Cephes poly + Cody-Waite) ---
// Bitwise-identical to numpy's AVX2/AVX512 expf for in-range inputs; this is
// what makes the binning bit-exact. DO NOT TOUCH.
__device__ __forceinline__ float np_expf(float x) {
    const float LOG2E = 1.442695040f;          // NPY_LOG2Ef -> 0x3FB8AA3B
    float z = x * LOG2E;
    float q = __builtin_rintf(z);              // round-to-nearest-even
    float r = __builtin_fmaf(q, -0.693359375f, x);
    r = __builtin_fmaf(q, 2.12194440e-4f, r);
    float rr = r * r;
    float p = 1.9875691500e-4f;
    p = __builtin_fmaf(p, r, 1.3981999507e-3f);
    p = __builtin_fmaf(p, r, 8.3334519073e-3f);
    p = __builtin_fmaf(p, r, 4.1665795894e-2f);
    p = __builtin_fmaf(p, r, 1.6666665459e-1f);
    p = __builtin_fmaf(p, r, 5.0000001201e-1f);
    p = __builtin_fmaf(p, rr, r);
    p = p + 1.0f;
    return ldexpf(p, (int)q);
}

// Reference (plan-B) exact binning: full IEEE f32 div.
__device__ __forceinline__ int bin_index_ref(float x, float t) {
    float e = np_expf(-x);
    float p = 1.0f / (1.0f + e);               // correctly-rounded f32 div
    float g = fabsf(p - t);
    float d = g * 10.0f;
    int idx = (int)d;
    return idx > (NBINS - 1) ? (NBINS - 1) : idx;
}

// Fast binning for one float4 group: v_rcp_f32 sigmoid (<=1ulp => |d_fast -
// d_exact| <= ~3e-6). If any fractional part is within BMARG (2e-5) of a bin
// edge, recompute the whole group with the exact IEEE div — so the returned
// bins are ALWAYS bit-identical to the reference chain. Also accumulates the
// packed-u64 histogram (6 bits per bin; caller drains before overflow) and
// returns the 4 bin indices packed one-per-byte (little-endian).
__device__ __forceinline__ unsigned bin4(float4 x, float4 t,
                                         unsigned long long& a64) {
    float e0 = np_expf(-x.x), e1 = np_expf(-x.y);
    float e2 = np_expf(-x.z), e3 = np_expf(-x.w);
    float s0 = 1.0f + e0, s1 = 1.0f + e1, s2 = 1.0f + e2, s3 = 1.0f + e3;
    float d0 = fabsf(__builtin_amdgcn_rcpf(s0) - t.x) * 10.0f;
    float d1 = fabsf(__builtin_amdgcn_rcpf(s1) - t.y) * 10.0f;
    float d2 = fabsf(__builtin_amdgcn_rcpf(s2) - t.z) * 10.0f;
    float d3 = fabsf(__builtin_amdgcn_rcpf(s3) - t.w) * 10.0f;
    int i0 = (int)d0, i1 = (int)d1, i2 = (int)d2, i3 = (int)d3;
    float f0 = d0 - (float)i0, f1 = d1 - (float)i1;
    float f2 = d2 - (float)i2, f3 = d3 - (float)i3;
    float fmn = fminf(fminf(f0, f1), fminf(f2, f3));
    float fmx = fmaxf(fmaxf(f0, f1), fmaxf(f2, f3));
    if (fmn < BMARG || fmx > 1.0f - BMARG) {   // rare (~1% of wave-groups)
        d0 = fabsf(1.0f / s0 - t.x) * 10.0f; i0 = (int)d0;
        d1 = fabsf(1.0f / s1 - t.y) * 10.0f; i1 = (int)d1;
        d2 = fabsf(1.0f / s2 - t.z) * 10.0f; i2 = (int)d2;
        d3 = fabsf(1.0f / s3 - t.w) * 10.0f; i3 = (int)d3;
    }
    i0 = i0 > 9 ? 9 : i0; i1 = i1 > 9 ? 9 : i1;
    i2 = i2 > 9 ? 9 : i2; i3 = i3 > 9 ? 9 : i3;
    a64 += (1ULL << (i0 * 6)) + (1ULL << (i1 * 6)) +
           (1ULL << (i2 * 6)) + (1ULL << (i3 * 6));
    return (unsigned)i0 | ((unsigned)i1 << 8) |
           ((unsigned)i2 << 16) | ((unsigned)i3 << 24);
}

__device__ __forceinline__ int bin1(float x, float t) {
    float e = np_expf(-x);
    float s = 1.0f + e;
    float d = fabsf(__builtin_amdgcn_rcpf(s) - t) * 10.0f;
    int di = (int)d;
    float f = d - (float)di;
    if (f < BMARG || f > 1.0f - BMARG) {
        d = fabsf(1.0f / s - t) * 10.0f;
        di = (int)d;
    }
    return di > 9 ? 9 : di;
}

// Stable BCE; only needs ~1e-6 relative (binning carries the exactness).
__device__ __forceinline__ float bce1(float x, float t) {
    float e = __expf(-fabsf(x));
    return fmaxf(x, 0.0f) - x * t + __logf(1.0f + e);
}

__device__ __forceinline__ void nt_store(float4* p, float4 v) {
    __builtin_nontemporal_store(*(f32x4*)&v, (f32x4*)p);
}

#define DRAIN64()                                                        \
    do {                                                                 \
        _Pragma("unroll")                                                \
        for (int b = 0; b < NBINS; ++b)                                  \
            c[b] += (unsigned)((a64 >> (6 * b)) & 63ULL);                \
        a64 = 0ULL;                                                      \
    } while (0)

// ============================= PLAN A ====================================
// Pass 1: bin once, store packed idx bytes + per-block histogram (plain
// stores, bin-major [NBINS][nblocks] — no atomics, no init kernel needed).
__global__ void __launch_bounds__(256, 4)
ghm_pass1_k(const float4* __restrict__ x4, const float4* __restrict__ t4,
            const float* __restrict__ x1, const float* __restrict__ t1,
            unsigned int* __restrict__ idxw,     // n/4 u32 words (byte k = idx of elem k)
            unsigned int* __restrict__ bcounts,  // [NBINS][nblocks]
            int n4, int n, int nblocks) {
    unsigned c[NBINS];
#pragma unroll
    for (int i = 0; i < NBINS; ++i) c[i] = 0u;
    unsigned long long a64 = 0ULL;
    int since = 0;

    int gsz = gridDim.x * blockDim.x;
    int tid = blockIdx.x * blockDim.x + threadIdx.x;
    int nChunk = n4 >> 2;                        // chunks of 4 float4 = 16 elems
    for (int ch = tid; ch < nChunk; ch += gsz) {
        int j = ch << 2;
        float4 xa = x4[j],     xb = x4[j + 1],  xc = x4[j + 2],  xd = x4[j + 3];
        float4 ta = t4[j],     tb = t4[j + 1],  tc = t4[j + 2],  td = t4[j + 3];
        uint4 P;
        P.x = bin4(xa, ta, a64);
        P.y = bin4(xb, tb, a64);
        P.z = bin4(xc, tc, a64);
        P.w = bin4(xd, td, a64);
        ((uint4*)idxw)[ch] = P;
        if (++since == 3) { since = 0; DRAIN64(); }   // 3*16=48 <= 63 per field
    }
    DRAIN64();

    // remainder float4 groups + scalar tail (block 0 only; <= 3 each total)
    if (blockIdx.x == 0) {
        for (int j = (nChunk << 2) + (int)threadIdx.x; j < n4; j += blockDim.x) {
            float4 x = x4[j], t = t4[j];
            idxw[j] = bin4(x, t, a64);
        }
        int tail = n - n4 * 4;
        if ((int)threadIdx.x < tail) {
            int k = n4 * 4 + threadIdx.x;
            int ix = bin1(x1[k], t1[k]);
            ((unsigned char*)idxw)[k] = (unsigned char)ix;
            a64 += 1ULL << (ix * 6);
        }
        DRAIN64();
    }

    __shared__ unsigned ls[4][NBINS];
    int lane = threadIdx.x & 63;
    int wv = threadIdx.x >> 6;
#pragma unroll
    for (int b = 0; b < NBINS; ++b) {
        unsigned v = c[b];
#pragma unroll
        for (int off = 32; off > 0; off >>= 1)
            v += __shfl_down(v, off, 64);
        if (lane == 0) ls[wv][b] = v;
    }
    __syncthreads();
    if (threadIdx.x < NBINS) {
        unsigned s = ls[0][threadIdx.x] + ls[1][threadIdx.x] +
                     ls[2][threadIdx.x] + ls[3][threadIdx.x];
        bcounts[threadIdx.x * nblocks + blockIdx.x] = s;   // plain store
    }
}

// Reduce [NBINS][nblocks] -> W[10] (pre-divided by TOT_F). 640 threads:
// wave b reduces bin b (lanes stride the block axis), no atomics.
__global__ void ghm_wreduce_k(const unsigned int* __restrict__ bc,
                              float* __restrict__ W, int nblocks) {
    __shared__ unsigned tot[NBINS];
    int b = threadIdx.x >> 6, r = threadIdx.x & 63;
    unsigned s = 0;
    for (int j = r; j < nblocks; j += 64) s += bc[b * nblocks + j];
#pragma unroll
    for (int off = 32; off > 0; off >>= 1) s += __shfl_down(s, off, 64);
    if (r == 0) tot[b] = s;
    __syncthreads();
    if (threadIdx.x == 0) {
        int nn = 0;
        for (int i = 0; i < NBINS; ++i) nn += (tot[i] > 0u);
        float nf = fmaxf((float)nn, 1.0f);
        for (int i = 0; i < NBINS; ++i) {
            float cf = (float)tot[i];    // counts < 2^24: exact
            float bw = (tot[i] > 0u) ? (TOT_F / fmaxf(cf, 1.0f)) : 0.0f;
            W[i] = (bw / nf) / TOT_F;    // fold final /tot into the table
        }
    }
}

__device__ __forceinline__ float4 apply4(float4 x, float4 t, unsigned pk,
                                         const float* __restrict__ sW) {
    float4 o;
    o.x = sW[pk & 255u]         * bce1(x.x, t.x);
    o.y = sW[(pk >> 8) & 255u]  * bce1(x.y, t.y);
    o.z = sW[(pk >> 16) & 255u] * bce1(x.z, t.z);
    o.w = sW[pk >> 24]          * bce1(x.w, t.w);
    return o;
}

// Pass 2: read idx + x,t, recompute cheap BCE, scale, store. Iterates in
// REVERSE chunk order: starts on the tail pass 1 just left hot in L3, and
// leaves the head hot for the next iteration's pass 1.
__global__ void __launch_bounds__(256, 4)
ghm_apply_k(const float4* __restrict__ x4, const float4* __restrict__ t4,
            const float* __restrict__ x1, const float* __restrict__ t1,
            const unsigned int* __restrict__ idxw,
            const float* __restrict__ W,
            float4* __restrict__ o4, float* __restrict__ o1,
            int n4, int n) {
    __shared__ float sW[NBINS];
    if (threadIdx.x < NBINS) sW[threadIdx.x] = W[threadIdx.x];
    __syncthreads();

    int gsz = gridDim.x * blockDim.x;
    int tid = blockIdx.x * blockDim.x + threadIdx.x;
    int nChunk = n4 >> 2;
    for (int ch = tid; ch < nChunk; ch += gsz) {
        int cr = nChunk - 1 - ch;                 // reverse sweep
        int j = cr << 2;
        uint4 P = ((const uint4*)idxw)[cr];
        float4 xa = x4[j],     xb = x4[j + 1],  xc = x4[j + 2],  xd = x4[j + 3];
        float4 ta = t4[j],     tb = t4[j + 1],  tc = t4[j + 2],  td = t4[j + 3];
        nt_store(&o4[j],     apply4(xa, ta, P.x, sW));
        nt_store(&o4[j + 1], apply4(xb, tb, P.y, sW));
        nt_store(&o4[j + 2], apply4(xc, tc, P.z, sW));
        nt_store(&o4[j + 3], apply4(xd, td, P.w, sW));
    }
    if (blockIdx.x == 0) {
        for (int j = (nChunk << 2) + (int)threadIdx.x; j < n4; j += blockDim.x) {
            float4 x = x4[j], t = t4[j];
            nt_store(&o4[j], apply4(x, t, idxw[j], sW));
        }
        int tail = n - n4 * 4;
        if ((int)threadIdx.x < tail) {
            int k = n4 * 4 + threadIdx.x;
            o1[k] = sW[((const unsigned char*)idxw)[k]] * bce1(x1[k], t1[k]);
        }
    }
}

// ======================= PLAN B (ws too small) ===========================
// Verbatim round-1 structure (proven): replica-atomic hist + full recompute.
__global__ void ghm_init_k(unsigned int* __restrict__ counts) {
    int i = threadIdx.x;
    if (i < NREPL * REPL_STRIDE) counts[i] = 0u;
}

__device__ __forceinline__ void acc4(unsigned int c[NBINS], float4 x, float4 t) {
    int i0 = bin_index_ref(x.x, t.x);
    int i1 = bin_index_ref(x.y, t.y);
    int i2 = bin_index_ref(x.z, t.z);
    int i3 = bin_index_ref(x.w, t.w);
#pragma unroll
    for (int b = 0; b < NBINS; ++b)
        c[b] += (unsigned int)(i0 == b) + (unsigned int)(i1 == b) +
                (unsigned int)(i2 == b) + (unsigned int)(i3 == b);
}

__global__ void __launch_bounds__(256, 4)
ghm_hist_k(const float4* __restrict__ x4, const float4* __restrict__ t4,
           const float* __restrict__ x1, const float* __restrict__ t1,
           unsigned int* __restrict__ counts, int n4, int n) {
    unsigned int c[NBINS];
#pragma unroll
    for (int i = 0; i < NBINS; ++i) c[i] = 0u;
    int gsz = gridDim.x * blockDim.x;
    int i = blockIdx.x * blockDim.x + threadIdx.x;
    int lim = n4 - 3 * gsz;
    for (; i < lim; i += 4 * gsz) {
        float4 xa = x4[i], xb = x4[i + gsz], xc = x4[i + 2 * gsz], xd = x4[i + 3 * gsz];
        float4 ta = t4[i], tb = t4[i + gsz], tc = t4[i + 2 * gsz], td = t4[i + 3 * gsz];
        acc4(c, xa, ta); acc4(c, xb, tb); acc4(c, xc, tc); acc4(c, xd, td);
    }
    for (; i < n4; i += gsz) { float4 x = x4[i], t = t4[i]; acc4(c, x, t); }
    int tail = n - n4 * 4;
    if (blockIdx.x == 0 && (int)threadIdx.x < tail) {
        int k = n4 * 4 + threadIdx.x;
        int ix = bin_index_ref(x1[k], t1[k]);
#pragma unroll
        for (int b = 0; b < NBINS; ++b) c[b] += (unsigned int)(ix == b);
    }
    __shared__ unsigned int ls[4][NBINS];
    int lane = threadIdx.x & 63, wv = threadIdx.x >> 6;
#pragma unroll
    for (int b = 0; b < NBINS; ++b) {
        unsigned int v = c[b];
#pragma unroll
        for (int off = 32; off > 0; off >>= 1) v += __shfl_down(v, off, 64);
        if (lane == 0) ls[wv][b] = v;
    }
    __syncthreads();
    if (threadIdx.x < NBINS) {
        unsigned int s = ls[0][threadIdx.x] + ls[1][threadIdx.x] +
                         ls[2][threadIdx.x] + ls[3][threadIdx.x];
        if (s) atomicAdd(&counts[(blockIdx.x & 63) * REPL_STRIDE + threadIdx.x], s);
    }
}

__global__ void ghm_weights_k(const unsigned int* __restrict__ counts,
                              float* __restrict__ W) {
    __shared__ unsigned int tot[NBINS];
    if (threadIdx.x < NBINS) tot[threadIdx.x] = 0u;
    __syncthreads();
    if (threadIdx.x < NREPL * NBINS) {
        int r = threadIdx.x / NBINS, b = threadIdx.x % NBINS;
        unsigned int v = counts[r * REPL_STRIDE + b];
        if (v) atomicAdd(&tot[b], v);
    }
    __syncthreads();
    if (threadIdx.x == 0) {
        int nn = 0;
        for (int i = 0; i < NBINS; ++i) nn += (tot[i] > 0u);
        float nf = fmaxf((float)nn, 1.0f);
        for (int i = 0; i < NBINS; ++i) {
            float cf = (float)tot[i];
            float bw = (tot[i] > 0u) ? (TOT_F / fmaxf(cf, 1.0f)) : 0.0f;
            W[i] = (bw / nf) / TOT_F;
        }
    }
}

__global__ void __launch_bounds__(256, 4)
ghm_main_k(const float4* __restrict__ x4, const float4* __restrict__ t4,
           const float* __restrict__ x1, const float* __restrict__ t1,
           const float* __restrict__ W,
           float4* __restrict__ o4, float* __restrict__ o1, int n4, int n) {
    __shared__ float sW[NBINS];
    if (threadIdx.x < NBINS) sW[threadIdx.x] = W[threadIdx.x];
    __syncthreads();
    int gsz = gridDim.x * blockDim.x;
    int i = blockIdx.x * blockDim.x + threadIdx.x;
    for (; i < n4; i += gsz) {
        float4 x = x4[i], t = t4[i];
        float4 o;
        o.x = sW[bin_index_ref(x.x, t.x)] * bce1(x.x, t.x);
        o.y = sW[bin_index_ref(x.y, t.y)] * bce1(x.y, t.y);
        o.z = sW[bin_index_ref(x.z, t.z)] * bce1(x.z, t.z);
        o.w = sW[bin_index_ref(x.w, t.w)] * bce1(x.w, t.w);
        nt_store(&o4[i], o);
    }
    int tail = n - n4 * 4;
    if (blockIdx.x == 0 && (int)threadIdx.x < tail) {
        int k = n4 * 4 + threadIdx.x;
        o1[k] = sW[bin_index_ref(x1[k], t1[k])] * bce1(x1[k], t1[k]);
    }
}

extern "C" void kernel_launch(void* const* d_in, const int* in_sizes, int n_in,
                              void* d_out, int out_size, void* d_ws, size_t ws_size,
                              hipStream_t stream) {
    const float* x = (const float*)d_in[0];
    const float* t = (const float*)d_in[1];
    float* out = (float*)d_out;
    int n  = in_sizes[0];
    int n4 = n >> 2;

    const int threads = 256;
    const int blocks  = 2048;   // 8 workgroups/CU on 256 CUs

    size_t idxBytes = ((size_t)n + 15) & ~(size_t)15;
    size_t cntOff   = idxBytes;
    size_t cntBytes = (size_t)blocks * NBINS * sizeof(unsigned);
    size_t wOff     = cntOff + ((cntBytes + 63) & ~(size_t)63);
    size_t need     = wOff + 64;

    if (ws_size >= need) {
        // -------- plan A: bin once, trivial second pass --------
        unsigned int* idxw    = (unsigned int*)d_ws;
        unsigned int* bcounts = (unsigned int*)((char*)d_ws + cntOff);
        float* W              = (float*)((char*)d_ws + wOff);

        ghm_pass1_k<<<blocks, threads, 0, stream>>>(
            (const float4*)x, (const float4*)t, x, t, idxw, bcounts, n4, n, blocks);
        ghm_wreduce_k<<<1, 640, 0, stream>>>(bcounts, W, blocks);
        ghm_apply_k<<<blocks, threads, 0, stream>>>(
            (const float4*)x, (const float4*)t, x, t, idxw, W,
            (float4*)out, out, n4, n);
    } else {
        // -------- plan B: proven round-1 path --------
        unsigned int* counts = (unsigned int*)d_ws;
        float* W = (float*)((char*)d_ws + NREPL * REPL_STRIDE * 4);
        ghm_init_k<<<1, 1024, 0, stream>>>(counts);
        ghm_hist_k<<<blocks, threads, 0, stream>>>(
            (const float4*)x, (const float4*)t, x, t, counts, n4, n);
        ghm_weights_k<<<1, 1024, 0, stream>>>(counts, W);
        ghm_main_k<<<blocks, threads, 0, stream>>>(
            (const float4*)x, (const float4*)t, x, t, W,
            (float4*)out, out, n4, n);
    }
}

// Round 3
// 592.464 us; speedup vs baseline: 1.3448x; 1.3448x over previous
//
#include <hip/hip_runtime.h>
#include <math.h>

#define NBINS 10
#define TOT_F 51200000.0f
#define BMARG 1e-4f       // edge margin for the hw-exp/rcp screen (err <= ~1.4e-5)
#define NREPL 64          // plan-B atomic replica lines
#define REPL_STRIDE 16

typedef float f32x4 __attribute__((ext_vector_type(4)));

// --- numpy float32 np.exp replica (SIMD path: Cephes poly + Cody-Waite) ---
// Bitwise-identical to numpy's AVX2/AVX512 expf for in-range inputs; this is
// what makes the binning bit-exact. DO NOT TOUCH.
__device__ __forceinline__ float np_expf(float x) {
    const float LOG2E = 1.442695040f;          // NPY_LOG2Ef -> 0x3FB8AA3B
    float z = x * LOG2E;
    float q = __builtin_rintf(z);              // round-to-nearest-even
    float r = __builtin_fmaf(q, -0.693359375f, x);
    r = __builtin_fmaf(q, 2.12194440e-4f, r);
    float rr = r * r;
    float p = 1.9875691500e-4f;
    p = __builtin_fmaf(p, r, 1.3981999507e-3f);
    p = __builtin_fmaf(p, r, 8.3334519073e-3f);
    p = __builtin_fmaf(p, r, 4.1665795894e-2f);
    p = __builtin_fmaf(p, r, 1.6666665459e-1f);
    p = __builtin_fmaf(p, r, 5.0000001201e-1f);
    p = __builtin_fmaf(p, rr, r);
    p = p + 1.0f;
    return ldexpf(p, (int)q);
}

// Exact reference binning chain (numpy-faithful): used for the rare
// near-edge fallback, the scalar tail, and plan B.
__device__ __forceinline__ int bin_index_ref(float x, float t) {
    float e = np_expf(-x);
    float p = 1.0f / (1.0f + e);               // correctly-rounded f32 div
    float g = fabsf(p - t);
    float d = g * 10.0f;
    int idx = (int)d;                          // d >= 0: trunc == floor
    return idx > (NBINS - 1) ? (NBINS - 1) : idx;
}

// Fast binning for one float4 group. Screen path uses HW v_exp/v_rcp
// (|d_fast - d_ref| <= ~1.4e-5). If any element's d is within BMARG=1e-4 of
// an integer bin edge, the whole group recomputes through the exact numpy
// chain — so returned bins are ALWAYS bit-identical to the reference.
// Also accumulates the packed-u64 histogram (6 bits/bin, caller drains) and
// returns the 4 bin indices packed one per byte (little-endian).
__device__ __forceinline__ unsigned bin4(float4 x, float4 t,
                                         unsigned long long& a64) {
    float e0 = __expf(-x.x), e1 = __expf(-x.y);
    float e2 = __expf(-x.z), e3 = __expf(-x.w);
    float d0 = fabsf(__builtin_amdgcn_rcpf(1.0f + e0) - t.x) * 10.0f;
    float d1 = fabsf(__builtin_amdgcn_rcpf(1.0f + e1) - t.y) * 10.0f;
    float d2 = fabsf(__builtin_amdgcn_rcpf(1.0f + e2) - t.z) * 10.0f;
    float d3 = fabsf(__builtin_amdgcn_rcpf(1.0f + e3) - t.w) * 10.0f;
    int i0 = (int)d0, i1 = (int)d1, i2 = (int)d2, i3 = (int)d3;
    float f0 = d0 - (float)i0, f1 = d1 - (float)i1;
    float f2 = d2 - (float)i2, f3 = d3 - (float)i3;
    float fmn = fminf(fminf(f0, f1), fminf(f2, f3));
    float fmx = fmaxf(fmaxf(f0, f1), fmaxf(f2, f3));
    if (fmn < BMARG || fmx > 1.0f - BMARG) {   // ~2e-4 of groups
        i0 = bin_index_ref(x.x, t.x);
        i1 = bin_index_ref(x.y, t.y);
        i2 = bin_index_ref(x.z, t.z);
        i3 = bin_index_ref(x.w, t.w);
    }
    i0 = i0 > 9 ? 9 : i0; i1 = i1 > 9 ? 9 : i1;
    i2 = i2 > 9 ? 9 : i2; i3 = i3 > 9 ? 9 : i3;
    a64 += (1ULL << (i0 * 6)) + (1ULL << (i1 * 6)) +
           (1ULL << (i2 * 6)) + (1ULL << (i3 * 6));
    return (unsigned)i0 | ((unsigned)i1 << 8) |
           ((unsigned)i2 << 16) | ((unsigned)i3 << 24);
}

// Stable BCE; only needs ~1e-6 relative (binning carries the exactness).
__device__ __forceinline__ float bce1(float x, float t) {
    float e = __expf(-fabsf(x));
    return fmaxf(x, 0.0f) - x * t + __logf(1.0f + e);
}

__device__ __forceinline__ void nt_store(float4* p, float4 v) {
    __builtin_nontemporal_store(*(f32x4*)&v, (f32x4*)p);
}

#define DRAIN64()                                                        \
    do {                                                                 \
        _Pragma("unroll")                                                \
        for (int b = 0; b < NBINS; ++b)                                  \
            c[b] += (unsigned)((a64 >> (6 * b)) & 63ULL);                \
        a64 = 0ULL;                                                      \
    } while (0)

// ============================= PLAN A ====================================
// Pass 1: bin once (cheap screen + exact fallback), store idx bytes +
// per-block histogram with plain stores. FLAT thread-contiguous layout:
// every load/store instruction is a dense 1KB/wave access.
__global__ void __launch_bounds__(256, 4)
ghm_pass1_k(const float4* __restrict__ x4, const float4* __restrict__ t4,
            const float* __restrict__ x1, const float* __restrict__ t1,
            unsigned int* __restrict__ idxw,     // n/4 u32 words
            unsigned int* __restrict__ bcounts,  // [NBINS][nblocks]
            int n4, int n, int nblocks) {
    unsigned c[NBINS];
#pragma unroll
    for (int i = 0; i < NBINS; ++i) c[i] = 0u;
    unsigned long long a64 = 0ULL;
    int since = 0;

    int gsz = gridDim.x * blockDim.x;
    int i = blockIdx.x * blockDim.x + threadIdx.x;
    int lim = n4 - 3 * gsz;
    for (; i < lim; i += 4 * gsz) {
        float4 xa = x4[i],           xb = x4[i + gsz];
        float4 xc = x4[i + 2 * gsz], xd = x4[i + 3 * gsz];
        float4 ta = t4[i],           tb = t4[i + gsz];
        float4 tc = t4[i + 2 * gsz], td = t4[i + 3 * gsz];
        idxw[i]           = bin4(xa, ta, a64);
        idxw[i + gsz]     = bin4(xb, tb, a64);
        idxw[i + 2 * gsz] = bin4(xc, tc, a64);
        idxw[i + 3 * gsz] = bin4(xd, td, a64);
        if (++since == 3) { since = 0; DRAIN64(); }   // 3*16=48 <= 63/field
    }
    DRAIN64();
    for (; i < n4; i += gsz) {          // <= 3 groups/thread (12 <= 63)
        float4 x = x4[i], t = t4[i];
        idxw[i] = bin4(x, t, a64);
    }
    DRAIN64();

    // scalar tail (block 0 only; n % 4 elements, exact chain directly)
    int tail = n - n4 * 4;
    if (blockIdx.x == 0 && (int)threadIdx.x < tail) {
        int k = n4 * 4 + threadIdx.x;
        int ix = bin_index_ref(x1[k], t1[k]);
        ((unsigned char*)idxw)[k] = (unsigned char)ix;
        c[0] += 0u;  // keep shape; count added below
        atomicAdd(&c[0], 0u); // no-op to avoid compiler confusion
        c[ix] += 1u;
    }

    __shared__ unsigned ls[4][NBINS];
    int lane = threadIdx.x & 63;
    int wv = threadIdx.x >> 6;
#pragma unroll
    for (int b = 0; b < NBINS; ++b) {
        unsigned v = c[b];
#pragma unroll
        for (int off = 32; off > 0; off >>= 1)
            v += __shfl_down(v, off, 64);
        if (lane == 0) ls[wv][b] = v;
    }
    __syncthreads();
    if (threadIdx.x < NBINS) {
        unsigned s = ls[0][threadIdx.x] + ls[1][threadIdx.x] +
                     ls[2][threadIdx.x] + ls[3][threadIdx.x];
        bcounts[threadIdx.x * nblocks + blockIdx.x] = s;   // plain store
    }
}

// Reduce [NBINS][nblocks] -> W[10] (pre-divided by TOT_F). Wave b reduces
// bin b; no atomics.
__global__ void ghm_wreduce_k(const unsigned int* __restrict__ bc,
                              float* __restrict__ W, int nblocks) {
    __shared__ unsigned tot[NBINS];
    int b = threadIdx.x >> 6, r = threadIdx.x & 63;
    unsigned s = 0;
    for (int j = r; j < nblocks; j += 64) s += bc[b * nblocks + j];
#pragma unroll
    for (int off = 32; off > 0; off >>= 1) s += __shfl_down(s, off, 64);
    if (r == 0) tot[b] = s;
    __syncthreads();
    if (threadIdx.x == 0) {
        int nn = 0;
        for (int i = 0; i < NBINS; ++i) nn += (tot[i] > 0u);
        float nf = fmaxf((float)nn, 1.0f);
        for (int i = 0; i < NBINS; ++i) {
            float cf = (float)tot[i];    // counts < 2^24: exact
            float bw = (tot[i] > 0u) ? (TOT_F / fmaxf(cf, 1.0f)) : 0.0f;
            W[i] = (bw / nf) / TOT_F;    // fold final /tot into the table
        }
    }
}

__device__ __forceinline__ float4 apply4(float4 x, float4 t, unsigned pk,
                                         const float* __restrict__ sW) {
    float4 o;
    o.x = sW[pk & 255u]         * bce1(x.x, t.x);
    o.y = sW[(pk >> 8) & 255u]  * bce1(x.y, t.y);
    o.z = sW[(pk >> 16) & 255u] * bce1(x.z, t.z);
    o.w = sW[pk >> 24]          * bce1(x.w, t.w);
    return o;
}

// Pass 2: read idx + x,t, recompute cheap BCE, scale, nt-store. FLAT
// thread-contiguous layout: all accesses fully coalesced, nt-stores pack
// whole cache lines.
__global__ void __launch_bounds__(256, 4)
ghm_apply_k(const float4* __restrict__ x4, const float4* __restrict__ t4,
            const float* __restrict__ x1, const float* __restrict__ t1,
            const unsigned int* __restrict__ idxw,
            const float* __restrict__ W,
            float4* __restrict__ o4, float* __restrict__ o1,
            int n4, int n) {
    __shared__ float sW[NBINS];
    if (threadIdx.x < NBINS) sW[threadIdx.x] = W[threadIdx.x];
    __syncthreads();

    int gsz = gridDim.x * blockDim.x;
    int i = blockIdx.x * blockDim.x + threadIdx.x;
    int lim = n4 - 3 * gsz;
    for (; i < lim; i += 4 * gsz) {
        float4 xa = x4[i],           xb = x4[i + gsz];
        float4 xc = x4[i + 2 * gsz], xd = x4[i + 3 * gsz];
        float4 ta = t4[i],           tb = t4[i + gsz];
        float4 tc = t4[i + 2 * gsz], td = t4[i + 3 * gsz];
        unsigned pa = idxw[i],           pb = idxw[i + gsz];
        unsigned pc = idxw[i + 2 * gsz], pd = idxw[i + 3 * gsz];
        nt_store(&o4[i],           apply4(xa, ta, pa, sW));
        nt_store(&o4[i + gsz],     apply4(xb, tb, pb, sW));
        nt_store(&o4[i + 2 * gsz], apply4(xc, tc, pc, sW));
        nt_store(&o4[i + 3 * gsz], apply4(xd, td, pd, sW));
    }
    for (; i < n4; i += gsz) {
        float4 x = x4[i], t = t4[i];
        nt_store(&o4[i], apply4(x, t, idxw[i], sW));
    }
    int tail = n - n4 * 4;
    if (blockIdx.x == 0 && (int)threadIdx.x < tail) {
        int k = n4 * 4 + threadIdx.x;
        o1[k] = sW[((const unsigned char*)idxw)[k]] * bce1(x1[k], t1[k]);
    }
}

// ======================= PLAN B (ws too small) ===========================
// Verbatim round-1 structure (proven): replica-atomic hist + full recompute.
__global__ void ghm_init_k(unsigned int* __restrict__ counts) {
    int i = threadIdx.x;
    if (i < NREPL * REPL_STRIDE) counts[i] = 0u;
}

__device__ __forceinline__ void acc4(unsigned int c[NBINS], float4 x, float4 t) {
    int i0 = bin_index_ref(x.x, t.x);
    int i1 = bin_index_ref(x.y, t.y);
    int i2 = bin_index_ref(x.z, t.z);
    int i3 = bin_index_ref(x.w, t.w);
#pragma unroll
    for (int b = 0; b < NBINS; ++b)
        c[b] += (unsigned int)(i0 == b) + (unsigned int)(i1 == b) +
                (unsigned int)(i2 == b) + (unsigned int)(i3 == b);
}

__global__ void __launch_bounds__(256, 4)
ghm_hist_k(const float4* __restrict__ x4, const float4* __restrict__ t4,
           const float* __restrict__ x1, const float* __restrict__ t1,
           unsigned int* __restrict__ counts, int n4, int n) {
    unsigned int c[NBINS];
#pragma unroll
    for (int i = 0; i < NBINS; ++i) c[i] = 0u;
    int gsz = gridDim.x * blockDim.x;
    int i = blockIdx.x * blockDim.x + threadIdx.x;
    int lim = n4 - 3 * gsz;
    for (; i < lim; i += 4 * gsz) {
        float4 xa = x4[i], xb = x4[i + gsz], xc = x4[i + 2 * gsz], xd = x4[i + 3 * gsz];
        float4 ta = t4[i], tb = t4[i + gsz], tc = t4[i + 2 * gsz], td = t4[i + 3 * gsz];
        acc4(c, xa, ta); acc4(c, xb, tb); acc4(c, xc, tc); acc4(c, xd, td);
    }
    for (; i < n4; i += gsz) { float4 x = x4[i], t = t4[i]; acc4(c, x, t); }
    int tail = n - n4 * 4;
    if (blockIdx.x == 0 && (int)threadIdx.x < tail) {
        int k = n4 * 4 + threadIdx.x;
        int ix = bin_index_ref(x1[k], t1[k]);
#pragma unroll
        for (int b = 0; b < NBINS; ++b) c[b] += (unsigned int)(ix == b);
    }
    __shared__ unsigned int ls[4][NBINS];
    int lane = threadIdx.x & 63, wv = threadIdx.x >> 6;
#pragma unroll
    for (int b = 0; b < NBINS; ++b) {
        unsigned int v = c[b];
#pragma unroll
        for (int off = 32; off > 0; off >>= 1) v += __shfl_down(v, off, 64);
        if (lane == 0) ls[wv][b] = v;
    }
    __syncthreads();
    if (threadIdx.x < NBINS) {
        unsigned int s = ls[0][threadIdx.x] + ls[1][threadIdx.x] +
                         ls[2][threadIdx.x] + ls[3][threadIdx.x];
        if (s) atomicAdd(&counts[(blockIdx.x & 63) * REPL_STRIDE + threadIdx.x], s);
    }
}

__global__ void ghm_weights_k(const unsigned int* __restrict__ counts,
                              float* __restrict__ W) {
    __shared__ unsigned int tot[NBINS];
    if (threadIdx.x < NBINS) tot[threadIdx.x] = 0u;
    __syncthreads();
    if (threadIdx.x < NREPL * NBINS) {
        int r = threadIdx.x / NBINS, b = threadIdx.x % NBINS;
        unsigned int v = counts[r * REPL_STRIDE + b];
        if (v) atomicAdd(&tot[b], v);
    }
    __syncthreads();
    if (threadIdx.x == 0) {
        int nn = 0;
        for (int i = 0; i < NBINS; ++i) nn += (tot[i] > 0u);
        float nf = fmaxf((float)nn, 1.0f);
        for (int i = 0; i < NBINS; ++i) {
            float cf = (float)tot[i];
            float bw = (tot[i] > 0u) ? (TOT_F / fmaxf(cf, 1.0f)) : 0.0f;
            W[i] = (bw / nf) / TOT_F;
        }
    }
}

__global__ void __launch_bounds__(256, 4)
ghm_main_k(const float4* __restrict__ x4, const float4* __restrict__ t4,
           const float* __restrict__ x1, const float* __restrict__ t1,
           const float* __restrict__ W,
           float4* __restrict__ o4, float* __restrict__ o1, int n4, int n) {
    __shared__ float sW[NBINS];
    if (threadIdx.x < NBINS) sW[threadIdx.x] = W[threadIdx.x];
    __syncthreads();
    int gsz = gridDim.x * blockDim.x;
    int i = blockIdx.x * blockDim.x + threadIdx.x;
    for (; i < n4; i += gsz) {
        float4 x = x4[i], t = t4[i];
        float4 o;
        o.x = sW[bin_index_ref(x.x, t.x)] * bce1(x.x, t.x);
        o.y = sW[bin_index_ref(x.y, t.y)] * bce1(x.y, t.y);
        o.z = sW[bin_index_ref(x.z, t.z)] * bce1(x.z, t.z);
        o.w = sW[bin_index_ref(x.w, t.w)] * bce1(x.w, t.w);
        nt_store(&o4[i], o);
    }
    int tail = n - n4 * 4;
    if (blockIdx.x == 0 && (int)threadIdx.x < tail) {
        int k = n4 * 4 + threadIdx.x;
        o1[k] = sW[bin_index_ref(x1[k], t1[k])] * bce1(x1[k], t1[k]);
    }
}

extern "C" void kernel_launch(void* const* d_in, const int* in_sizes, int n_in,
                              void* d_out, int out_size, void* d_ws, size_t ws_size,
                              hipStream_t stream) {
    const float* x = (const float*)d_in[0];
    const float* t = (const float*)d_in[1];
    float* out = (float*)d_out;
    int n  = in_sizes[0];
    int n4 = n >> 2;

    const int threads = 256;
    const int blocks  = 2048;   // 8 workgroups/CU on 256 CUs

    size_t idxBytes = ((size_t)n + 15) & ~(size_t)15;
    size_t cntOff   = idxBytes;
    size_t cntBytes = (size_t)blocks * NBINS * sizeof(unsigned);
    size_t wOff     = cntOff + ((cntBytes + 63) & ~(size_t)63);
    size_t need     = wOff + 64;

    if (ws_size >= need) {
        // -------- plan A: bin once, trivial second pass --------
        unsigned int* idxw    = (unsigned int*)d_ws;
        unsigned int* bcounts = (unsigned int*)((char*)d_ws + cntOff);
        float* W              = (float*)((char*)d_ws + wOff);

        ghm_pass1_k<<<blocks, threads, 0, stream>>>(
            (const float4*)x, (const float4*)t, x, t, idxw, bcounts, n4, n, blocks);
        ghm_wreduce_k<<<1, 640, 0, stream>>>(bcounts, W, blocks);
        ghm_apply_k<<<blocks, threads, 0, stream>>>(
            (const float4*)x, (const float4*)t, x, t, idxw, W,
            (float4*)out, out, n4, n);
    } else {
        // -------- plan B: proven round-1 path --------
        unsigned int* counts = (unsigned int*)d_ws;
        float* W = (float*)((char*)d_ws + NREPL * REPL_STRIDE * 4);
        ghm_init_k<<<1, 1024, 0, stream>>>(counts);
        ghm_hist_k<<<blocks, threads, 0, stream>>>(
            (const float4*)x, (const float4*)t, x, t, counts, n4, n);
        ghm_weights_k<<<1, 1024, 0, stream>>>(counts, W);
        ghm_main_k<<<blocks, threads, 0, stream>>>(
            (const float4*)x, (const float4*)t, x, t, W,
            (float4*)out, out, n4, n);
    }
}